// Round 1
// baseline (812.433 us; speedup 1.0000x reference)
//
#include <hip/hip_runtime.h>
#include <cfloat>
#include <math.h>

#define E 16
#define DFULL 1024
#define DM 128
#define S 64
#define P 2048
#define B 8
#define C 256
#define W 3
#define H 16

struct RoutesArg { int nb[E][W]; };

// ---------------- host: replicate _expert_routes() exactly ----------------
static void compute_routes(int r[E][W]) {
  float coords[E];
  for (int i = 0; i < E; ++i) {
    double x = (double)i / (double)(E - 1);
    if (x < 1e-06) x = 1e-06;
    if (x > 1.0 - 1e-06) x = 1.0 - 1e-06;
    double val = 0.0, factor = 0.5;
    for (int k = 0; k < 8; ++k) {
      x *= 3.0;
      int d = (int)x;
      x -= (double)d;
      if (d == 2) val += factor;
      factor *= 0.5;
    }
    coords[i] = (float)val;
  }
  for (int e = 0; e < E; ++e) {
    float de[E];
    for (int i = 0; i < E; ++i) de[i] = fabsf(coords[i] - coords[e]);
    bool used[E] = {false};
    for (int w = 0; w < W; ++w) {
      int best = -1; float bd = FLT_MAX;
      for (int i = 0; i < E; ++i)
        if (!used[i] && de[i] < bd) { bd = de[i]; best = i; }  // strict < = stable ties
      used[best] = true;
      r[e][w] = best;
    }
  }
}

__device__ __forceinline__ float gelu_tanh(float x) {
  float x3 = x * x * x;
  return 0.5f * x * (1.0f + tanhf(0.7978845608028654f * (x + 0.044715f * x3)));
}
__device__ __forceinline__ float sigmoidf(float x) {
  return 1.0f / (1.0f + __expf(-x));
}

// ---------------- K1: dispatch (idx prefix + counts) ----------------
__global__ __launch_bounds__(256) void k_dispatch(const float* __restrict__ fp,
                                                  int* __restrict__ idx,
                                                  int* __restrict__ counts) {
  int e = blockIdx.x, t = threadIdx.x;
  float lo = (float)e * 0.0625f, hi = (float)(e + 1) * 0.0625f;
  bool last = (e == E - 1);
  int p0 = t * 8;
  int m[8]; int ls = 0;
  #pragma unroll
  for (int k = 0; k < 8; ++k) {
    float f = fp[p0 + k];
    bool mm = (f >= lo) && (last ? (f <= hi) : (f < hi));
    m[k] = mm ? 1 : 0;
    ls += m[k];
  }
  __shared__ int sc[256];
  sc[t] = ls;
  __syncthreads();
  for (int o = 1; o < 256; o <<= 1) {
    int v = (t >= o) ? sc[t - o] : 0;
    __syncthreads();
    sc[t] += v;
    __syncthreads();
  }
  int incl = sc[t];
  int M = sc[255];
  int r = incl - ls;  // exclusive base
  #pragma unroll
  for (int k = 0; k < 8; ++k) {
    if (m[k]) {
      if (r < C) idx[e * C + r] = p0 + k;
      r++;
    }
  }
  if (t == 0) counts[e] = (M < C) ? M : C;
}

// ---------------- K2: gather + gate + Qaff/Kaff/V + kmin/kmax ----------------
__global__ __launch_bounds__(128) void k_p1(
    const float* __restrict__ tokens, const float* __restrict__ alpha,
    const float* __restrict__ gw1, const float* __restrict__ gb1,
    const float* __restrict__ gw2, const float* __restrict__ gb2,
    const float* __restrict__ qw, const float* __restrict__ kw,
    const float* __restrict__ vw, const float* __restrict__ penta,
    const int* __restrict__ idx, const int* __restrict__ counts,
    float* __restrict__ Vv, float* __restrict__ Qa, float* __restrict__ Ka,
    float* __restrict__ kmx, float* __restrict__ kmn) {
  int e = blockIdx.x, b = blockIdx.y, rh = blockIdx.z;
  int tid = threadIdx.x;
  int i = rh * 128 + tid;

  __shared__ float s_rn[5];
  __shared__ float s_qd[5][S];
  __shared__ float s_kd[5][S];
  __shared__ float s_max[5][128];
  __shared__ float s_min[5][128];
  __shared__ float s_f[128 * 65];  // padded feats tile (bank-conflict-free)

  if (tid < 5) {
    const float* pv = penta + (e * 5 + tid) * DM;
    float ss = 0.f;
    for (int d = 0; d < DM; ++d) ss += pv[d] * pv[d];
    s_rn[tid] = 1.0f / sqrtf(ss);
  }
  __syncthreads();
  for (int u = tid; u < 2 * 5 * S; u += 128) {
    int which = u / (5 * S);
    int rem = u - which * 5 * S;
    int v = rem / S, s = rem - v * S;
    const float* wrow = (which ? kw : qw) + (e * S + s) * DM;
    const float* pv = penta + (e * 5 + v) * DM;
    float acc = 0.f;
    for (int d = 0; d < DM; ++d) acc += wrow[d] * pv[d];
    float val = acc * s_rn[v];
    if (which) s_kd[v][s] = val; else s_qd[v][s] = val;
  }
  __syncthreads();

  int Me = counts[e];
  bool active = (i < Me);
  float ka[5] = {0.f, 0.f, 0.f, 0.f, 0.f};

  if (active) {
    int pos = idx[e * C + i];
    const float* trow = tokens + ((size_t)b * P + pos) * DFULL + e * S;
    float f[S];
    #pragma unroll
    for (int u = 0; u < S / 4; ++u) {
      float4 t4 = ((const float4*)trow)[u];
      f[u * 4 + 0] = t4.x; f[u * 4 + 1] = t4.y;
      f[u * 4 + 2] = t4.z; f[u * 4 + 3] = t4.w;
    }
    // gate MLP (16 hidden, uniform weights -> scalar loads)
    float hh[H];
    #pragma unroll
    for (int j = 0; j < H; ++j) hh[j] = gb1[e * H + j];
    #pragma unroll
    for (int s = 0; s < S; ++s) {
      float fs = f[s];
      #pragma unroll
      for (int j = 0; j < H; ++j) hh[j] += fs * gw1[(e * S + s) * H + j];
    }
    float z = gb2[e];
    #pragma unroll
    for (int j = 0; j < H; ++j) z += gelu_tanh(hh[j]) * gw2[e * H + j];
    float aw = sigmoidf(alpha[e]);
    float scl = sigmoidf(z) * aw + (1.0f - aw);
    #pragma unroll
    for (int s = 0; s < S; ++s) f[s] *= scl;

    // Qaff / Kaff via folded qd/kd
    #pragma unroll
    for (int v = 0; v < 5; ++v) {
      float aq = 0.f, ak = 0.f;
      #pragma unroll
      for (int s = 0; s < S; ++s) { aq += f[s] * s_qd[v][s]; ak += f[s] * s_kd[v][s]; }
      Qa[((e * 5 + v) * B + b) * C + i] = aq;
      Ka[((e * 5 + v) * B + b) * C + i] = ak;
      ka[v] = ak;
    }

    // stash gated feats in LDS (padded) for the V matmul's dynamic-s loop
    #pragma unroll
    for (int s = 0; s < S; ++s) s_f[tid * 65 + s] = f[s];

    // V = feats @ v_w   (v_w rows wave-uniform -> scalar loads)
    float acc[DM];
    #pragma unroll
    for (int d = 0; d < DM; ++d) acc[d] = 0.f;
    for (int s = 0; s < S; ++s) {
      float fs = s_f[tid * 65 + s];
      const float* vr = vw + (e * S + s) * DM;
      #pragma unroll
      for (int d = 0; d < DM; ++d) acc[d] += fs * vr[d];
    }
    float* vout = Vv + (((size_t)e * B + b) * C + i) * DM;
    #pragma unroll
    for (int d = 0; d < DM; d += 4) {
      float4 o4 = {acc[d], acc[d + 1], acc[d + 2], acc[d + 3]};
      *(float4*)(vout + d) = o4;
    }
  }

  // kmax/kmin over valid lanes of this row-half
  #pragma unroll
  for (int v = 0; v < 5; ++v) {
    s_max[v][tid] = active ? ka[v] : -FLT_MAX;
    s_min[v][tid] = active ? ka[v] : FLT_MAX;
  }
  __syncthreads();
  for (int s = 64; s > 0; s >>= 1) {
    if (tid < s) {
      #pragma unroll
      for (int v = 0; v < 5; ++v) {
        s_max[v][tid] = fmaxf(s_max[v][tid], s_max[v][tid + s]);
        s_min[v][tid] = fminf(s_min[v][tid], s_min[v][tid + s]);
      }
    }
    __syncthreads();
  }
  if (tid < 5) {
    kmx[((e * 5 + tid) * B + b) * 2 + rh] = s_max[tid][0];
    kmn[((e * 5 + tid) * B + b) * 2 + rh] = s_min[tid][0];
  }
}

// ---------------- K3: attention (thread = row, d-half per block) ----------------
__global__ __launch_bounds__(256) void k_p2(
    const float* __restrict__ Qa, const float* __restrict__ Ka,
    const float* __restrict__ Vv, const float* __restrict__ kmx,
    const float* __restrict__ kmn, const int* __restrict__ idx,
    const int* __restrict__ counts, const float* __restrict__ fusw,
    const float* __restrict__ temp, float* __restrict__ out, RoutesArg R) {
  int e = blockIdx.x, b = blockIdx.y, dh = blockIdx.z;
  int i = threadIdx.x;
  int Me = counts[e];
  if (i >= Me) return;

  int nbs[3] = {R.nb[e][0], R.nb[e][1], R.nb[e][2]};
  float invT = 1.0f / temp[0];

  // wdir = softmax(fusion_w)
  float fw[5];
  #pragma unroll
  for (int v = 0; v < 5; ++v) fw[v] = fusw[v];
  float fmx = fw[0];
  #pragma unroll
  for (int v = 1; v < 5; ++v) fmx = fmaxf(fmx, fw[v]);
  float fsum = 0.f;
  #pragma unroll
  for (int v = 0; v < 5; ++v) { fw[v] = __expf(fw[v] - fmx); fsum += fw[v]; }
  #pragma unroll
  for (int v = 0; v < 5; ++v) fw[v] /= fsum;

  // neighborhood-wide kmax/kmin per direction
  float KX[5], KN[5];
  #pragma unroll
  for (int v = 0; v < 5; ++v) {
    float mx = -FLT_MAX, mn = FLT_MAX;
    #pragma unroll
    for (int n = 0; n < 3; ++n) {
      int ne = nbs[n];
      int base = ((ne * 5 + v) * B + b) * 2;
      mx = fmaxf(mx, fmaxf(kmx[base + 0], kmx[base + 1]));
      mn = fminf(mn, fminf(kmn[base + 0], kmn[base + 1]));
    }
    KX[v] = mx; KN[v] = mn;
  }

  float q[5], m[5];
  #pragma unroll
  for (int v = 0; v < 5; ++v) {
    float qq = Qa[((e * 5 + v) * B + b) * C + i] * invT;
    q[v] = qq;
    m[v] = (qq > 0.f) ? qq * KX[v] : qq * KN[v];  // exact row max of scores
  }

  // pass 1: softmax denominators
  float l[5] = {0.f, 0.f, 0.f, 0.f, 0.f};
  for (int n = 0; n < 3; ++n) {
    int ne = nbs[n];
    int Mn = counts[ne];
    const float* kb = Ka + ((size_t)ne * 5 * B + b) * C;  // + v*B*C + j
    for (int j = 0; j < Mn; ++j) {
      #pragma unroll
      for (int v = 0; v < 5; ++v) l[v] += __expf(q[v] * kb[j + v * (B * C)] - m[v]);
    }
  }
  float c[5];
  #pragma unroll
  for (int v = 0; v < 5; ++v) c[v] = fw[v] / l[v];

  // pass 2: combined-weight @ V  (k & V rows wave-uniform -> scalar path)
  float acc[64];
  #pragma unroll
  for (int d = 0; d < 64; ++d) acc[d] = 0.f;
  for (int n = 0; n < 3; ++n) {
    int ne = nbs[n];
    int Mn = counts[ne];
    const float* kb = Ka + ((size_t)ne * 5 * B + b) * C;
    const float* vb = Vv + (((size_t)ne * B + b) * C) * DM + dh * 64;
    for (int j = 0; j < Mn; ++j) {
      float w = 0.f;
      #pragma unroll
      for (int v = 0; v < 5; ++v) w += c[v] * __expf(q[v] * kb[j + v * (B * C)] - m[v]);
      const float* vr = vb + (size_t)j * DM;
      #pragma unroll
      for (int d = 0; d < 64; ++d) acc[d] += w * vr[d];
    }
  }

  int pos = idx[e * C + i];
  float* orow = out + ((size_t)b * P + pos) * DM + dh * 64;
  #pragma unroll
  for (int d = 0; d < 64; d += 4) {
    float4 o4 = {acc[d], acc[d + 1], acc[d + 2], acc[d + 3]};
    *(float4*)(orow + d) = o4;
  }
}

// ---------------- launch ----------------
extern "C" void kernel_launch(void* const* d_in, const int* in_sizes, int n_in,
                              void* d_out, int out_size, void* d_ws, size_t ws_size,
                              hipStream_t stream) {
  const float* tokens = (const float*)d_in[0];
  const float* fingerprints = (const float*)d_in[1];
  const float* alpha = (const float*)d_in[2];
  const float* gw1 = (const float*)d_in[3];
  const float* gb1 = (const float*)d_in[4];
  const float* gw2 = (const float*)d_in[5];
  const float* gb2 = (const float*)d_in[6];
  const float* qw = (const float*)d_in[7];
  const float* kw = (const float*)d_in[8];
  const float* vw = (const float*)d_in[9];
  const float* penta = (const float*)d_in[10];
  const float* fusw = (const float*)d_in[11];
  const float* temp = (const float*)d_in[12];
  float* out = (float*)d_out;

  float* ws = (float*)d_ws;
  float* Vv = ws;                              // [E][B][C][DM]
  float* Qa = Vv + (size_t)E * B * C * DM;     // [E][5][B][C]
  float* Ka = Qa + (size_t)E * 5 * B * C;      // [E][5][B][C]
  float* kmx = Ka + (size_t)E * 5 * B * C;     // [E][5][B][2]
  float* kmn = kmx + (size_t)E * 5 * B * 2;    // [E][5][B][2]
  int* idx = (int*)(kmn + (size_t)E * 5 * B * 2);  // [E][C]
  int* counts = idx + (size_t)E * C;               // [E]

  RoutesArg R;
  compute_routes(R.nb);

  hipMemsetAsync(d_out, 0, (size_t)out_size * sizeof(float), stream);
  k_dispatch<<<dim3(E), dim3(256), 0, stream>>>(fingerprints, idx, counts);
  k_p1<<<dim3(E, B, 2), dim3(128), 0, stream>>>(tokens, alpha, gw1, gb1, gw2, gb2,
                                                qw, kw, vw, penta, idx, counts,
                                                Vv, Qa, Ka, kmx, kmn);
  k_p2<<<dim3(E, B, 2), dim3(256), 0, stream>>>(Qa, Ka, Vv, kmx, kmn, idx, counts,
                                                fusw, temp, out, R);
}

// Round 2
// 263.961 us; speedup vs baseline: 3.0779x; 3.0779x over previous
//
#include <hip/hip_runtime.h>
#include <cfloat>
#include <math.h>

#define E 16
#define DFULL 1024
#define DM 128
#define S 64
#define P 2048
#define B 8
#define C 256
#define W 3
#define H 16
#define NQK 10  /* 5 q-dirs then 5 k-dirs */

struct RoutesArg { int nb[E][W]; };

// ---------------- host: replicate _expert_routes() exactly ----------------
static void compute_routes(int r[E][W]) {
  float coords[E];
  for (int i = 0; i < E; ++i) {
    double x = (double)i / (double)(E - 1);
    if (x < 1e-06) x = 1e-06;
    if (x > 1.0 - 1e-06) x = 1.0 - 1e-06;
    double val = 0.0, factor = 0.5;
    for (int k = 0; k < 8; ++k) {
      x *= 3.0;
      int d = (int)x;
      x -= (double)d;
      if (d == 2) val += factor;
      factor *= 0.5;
    }
    coords[i] = (float)val;
  }
  for (int e = 0; e < E; ++e) {
    float de[E];
    for (int i = 0; i < E; ++i) de[i] = fabsf(coords[i] - coords[e]);
    bool used[E] = {false};
    for (int w = 0; w < W; ++w) {
      int best = -1; float bd = FLT_MAX;
      for (int i = 0; i < E; ++i)
        if (!used[i] && de[i] < bd) { bd = de[i]; best = i; }  // strict < = stable
      used[best] = true;
      r[e][w] = best;
    }
  }
}

__device__ __forceinline__ float gelu_tanh(float x) {
  float x3 = x * x * x;
  return 0.5f * x * (1.0f + tanhf(0.7978845608028654f * (x + 0.044715f * x3)));
}
__device__ __forceinline__ float sigmoidf_(float x) {
  return 1.0f / (1.0f + __expf(-x));
}

// identical-in-both-kernels row-max helper (determinism matters)
__device__ __forceinline__ void calc_m(const float* __restrict__ kmx,
                                       const float* __restrict__ kmn,
                                       const int nbs[3], int b,
                                       const float q[5], float m[5]) {
  #pragma unroll
  for (int v = 0; v < 5; ++v) {
    float KX = -FLT_MAX, KN = FLT_MAX;
    #pragma unroll
    for (int n = 0; n < 3; ++n) {
      int base = ((nbs[n] * 5 + v) * B + b) * 4;
      #pragma unroll
      for (int k = 0; k < 4; ++k) {
        KX = fmaxf(KX, kmx[base + k]);
        KN = fminf(KN, kmn[base + k]);
      }
    }
    m[v] = (q[v] > 0.f) ? q[v] * KX : q[v] * KN;  // exact max of valid scores
  }
}

// ---------------- K0: fold penta-norm and 1/T into qd/kd ----------------
__global__ __launch_bounds__(256) void k_prep(const float* __restrict__ qw,
                                              const float* __restrict__ kw,
                                              const float* __restrict__ penta,
                                              const float* __restrict__ temp,
                                              float* __restrict__ qkd) {
  int e = blockIdx.x, t = threadIdx.x;
  __shared__ float s_rn[5];
  if (t < 5) {
    const float* pv = penta + (e * 5 + t) * DM;
    float ss = 0.f;
    for (int d = 0; d < DM; ++d) ss += pv[d] * pv[d];
    s_rn[t] = 1.0f / sqrtf(ss);
  }
  __syncthreads();
  float invT = 1.0f / temp[0];
  int s = t & 63, cg = t >> 6;
  for (int c = cg; c < NQK; c += 4) {
    int v = c % 5;
    bool isq = (c < 5);
    const float* wrow = (isq ? qw : kw) + ((size_t)e * S + s) * DM;
    const float* pv = penta + (e * 5 + v) * DM;
    float acc = 0.f;
    #pragma unroll
    for (int d4 = 0; d4 < DM / 4; ++d4) {
      float4 a = ((const float4*)wrow)[d4];
      float4 p = ((const float4*)pv)[d4];
      acc += a.x * p.x + a.y * p.y + a.z * p.z + a.w * p.w;
    }
    qkd[(e * NQK + c) * S + s] = acc * s_rn[v] * (isq ? invT : 1.0f);
  }
}

// ---------------- K1: dispatch (idx prefix + counts) ----------------
__global__ __launch_bounds__(256) void k_dispatch(const float* __restrict__ fp,
                                                  int* __restrict__ idx,
                                                  int* __restrict__ counts) {
  int e = blockIdx.x, t = threadIdx.x;
  float lo = (float)e * 0.0625f, hi = (float)(e + 1) * 0.0625f;
  bool last = (e == E - 1);
  int p0 = t * 8;
  int m[8]; int ls = 0;
  #pragma unroll
  for (int k = 0; k < 8; ++k) {
    float f = fp[p0 + k];
    bool mm = (f >= lo) && (last ? (f <= hi) : (f < hi));
    m[k] = mm ? 1 : 0;
    ls += m[k];
  }
  __shared__ int sc[256];
  sc[t] = ls;
  __syncthreads();
  for (int o = 1; o < 256; o <<= 1) {
    int v = (t >= o) ? sc[t - o] : 0;
    __syncthreads();
    sc[t] += v;
    __syncthreads();
  }
  int incl = sc[t];
  int M = sc[255];
  int r = incl - ls;
  #pragma unroll
  for (int k = 0; k < 8; ++k) {
    if (m[k]) {
      if (r < C) idx[e * C + r] = p0 + k;
      r++;
    }
  }
  if (t == 0) counts[e] = (M < C) ? M : C;
}

// ---------------- K2: gate + Qa/Ka + V, 64-row quarters ----------------
__global__ __launch_bounds__(256) void k_p1(
    const float* __restrict__ tokens, const float* __restrict__ alpha,
    const float* __restrict__ gw1, const float* __restrict__ gb1,
    const float* __restrict__ gw2, const float* __restrict__ gb2,
    const float* __restrict__ vw, const float* __restrict__ qkd,
    const int* __restrict__ idx, const int* __restrict__ counts,
    float* __restrict__ Vv, float* __restrict__ Qa, float* __restrict__ Ka,
    float* __restrict__ kmx, float* __restrict__ kmn) {
  int e = blockIdx.x, b = blockIdx.y, rq = blockIdx.z;
  int t = threadIdx.x;
  int Me = counts[e];
  int r0 = rq * 64;

  if (r0 >= Me) {  // empty quarter: sentinels only
    if (t < 5) {
      kmx[((e * 5 + t) * B + b) * 4 + rq] = -FLT_MAX;
      kmn[((e * 5 + t) * B + b) * 4 + rq] = FLT_MAX;
    }
    return;
  }

  __shared__ float s_f[64 * 65];     // gated feats, stride 65 (conflict-free)
  __shared__ float s_qkd[NQK * S];   // folded q/k direction vectors
  __shared__ float s_kx[5 * 64];
  __shared__ float s_kn[5 * 64];

  // stage qkd (640 floats)
  if (t < NQK * S / 4) ((float4*)s_qkd)[t] = ((const float4*)(qkd + e * NQK * S))[t];

  // stage feats: 4 threads per row, 4 float4 each
  {
    int row = t >> 2, qo = t & 3;
    int i = r0 + row;
    int pos = (i < Me) ? idx[e * C + i] : 0;  // clamp garbage idx (OOB safety)
    const float* trow = tokens + ((size_t)b * P + pos) * DFULL + e * S;
    #pragma unroll
    for (int k = 0; k < 4; ++k) {
      float4 v4 = ((const float4*)trow)[qo + 4 * k];
      int so = (qo + 4 * k) * 4;
      s_f[row * 65 + so + 0] = v4.x;
      s_f[row * 65 + so + 1] = v4.y;
      s_f[row * 65 + so + 2] = v4.z;
      s_f[row * 65 + so + 3] = v4.w;
    }
  }
  __syncthreads();

  // gate (wave 0, thread = row), scale feats in place
  if (t < 64) {
    float hh[H];
    #pragma unroll
    for (int j = 0; j < H; ++j) hh[j] = gb1[e * H + j];
    for (int s = 0; s < S; ++s) {
      float fs = s_f[t * 65 + s];
      const float* gr = gw1 + ((size_t)e * S + s) * H;
      #pragma unroll
      for (int j = 0; j < H; ++j) hh[j] += fs * gr[j];
    }
    float z = gb2[e];
    #pragma unroll
    for (int j = 0; j < H; ++j) z += gelu_tanh(hh[j]) * gw2[e * H + j];
    float aw = sigmoidf_(alpha[e]);
    float scl = sigmoidf_(z) * aw + (1.0f - aw);
    for (int s = 0; s < S; ++s) s_f[t * 65 + s] *= scl;
  }
  __syncthreads();

  // Qa/Ka: thread = (row = t&63, wave = t>>6 picks c = cw, cw+4, cw+8)
  {
    int r = t & 63, cw = t >> 6;
    int ii = r0 + r;
    bool val = (ii < Me);
    for (int c = cw; c < NQK; c += 4) {
      float a = 0.f;
      #pragma unroll
      for (int s = 0; s < S; ++s) a += s_f[r * 65 + s] * s_qkd[c * S + s];
      int v = c % 5;
      if (c < 5) {
        if (val) Qa[((e * 5 + v) * B + b) * C + ii] = a;
      } else {
        if (val) Ka[((e * 5 + v) * B + b) * C + ii] = a;
        s_kx[v * 64 + r] = val ? a : -FLT_MAX;
        s_kn[v * 64 + r] = val ? a : FLT_MAX;
      }
    }
  }
  __syncthreads();
  if (t < 5) {
    float mx = -FLT_MAX, mn = FLT_MAX;
    for (int r = 0; r < 64; ++r) {
      mx = fmaxf(mx, s_kx[t * 64 + r]);
      mn = fminf(mn, s_kn[t * 64 + r]);
    }
    kmx[((e * 5 + t) * B + b) * 4 + rq] = mx;
    kmn[((e * 5 + t) * B + b) * 4 + rq] = mn;
  }

  // V = feats @ v_w : thread = (row = t&63, wave-uniform 32-d chunk)
  {
    int r = t & 63;
    int dch = (t >> 6) << 5;
    dch = __builtin_amdgcn_readfirstlane(dch);  // force wave-uniform address
    const float* vb = vw + (size_t)e * S * DM + dch;
    float acc[32];
    #pragma unroll
    for (int k = 0; k < 32; ++k) acc[k] = 0.f;
    for (int s = 0; s < S; ++s) {
      float fs = s_f[r * 65 + s];
      const float* vr = vb + s * DM;
      #pragma unroll
      for (int k = 0; k < 32; ++k) acc[k] += fs * vr[k];
    }
    int ii = r0 + r;
    if (ii < Me) {
      float* vo = Vv + (((size_t)(e * B + b)) * C + ii) * DM + dch;
      #pragma unroll
      for (int k = 0; k < 32; k += 4) {
        float4 o4 = {acc[k], acc[k + 1], acc[k + 2], acc[k + 3]};
        *(float4*)(vo + k) = o4;
      }
    }
  }
}

// ---------------- K3a: softmax denominators -> CL = wdir/l ----------------
__global__ __launch_bounds__(512) void k_p2l(
    const float* __restrict__ Qa, const float* __restrict__ Ka,
    const float* __restrict__ kmx, const float* __restrict__ kmn,
    const int* __restrict__ counts, const float* __restrict__ fusw,
    float* __restrict__ CL, RoutesArg R) {
  int e = blockIdx.x, b = blockIdx.y, rh = blockIdx.z;
  int t = threadIdx.x;
  int Me = counts[e];
  if (rh * 128 >= Me) return;
  int il = t & 127, jq = t >> 7;
  int i = rh * 128 + il;
  int nbs[3] = {R.nb[e][0], R.nb[e][1], R.nb[e][2]};

  float q[5], m[5];
  #pragma unroll
  for (int v = 0; v < 5; ++v) q[v] = Qa[((e * 5 + v) * B + b) * C + i];
  calc_m(kmx, kmn, nbs, b, q, m);

  float lp[5] = {0.f, 0.f, 0.f, 0.f, 0.f};
  for (int n = 0; n < 3; ++n) {
    int ne = nbs[n];
    int Mn = counts[ne];
    int chunk = (Mn + 3) >> 2;
    int j0 = jq * chunk;
    int j1 = j0 + chunk; if (j1 > Mn) j1 = Mn;
    const float* kb = Ka + ((size_t)(ne * 5) * B + b) * C;
    for (int j = j0; j < j1; ++j) {
      #pragma unroll
      for (int v = 0; v < 5; ++v)
        lp[v] += __expf(q[v] * kb[v * (B * C) + j] - m[v]);
    }
  }
  __shared__ float s_lp[4][128][5];
  #pragma unroll
  for (int v = 0; v < 5; ++v) s_lp[jq][il][v] = lp[v];
  __syncthreads();
  if (t < 128) {
    // wdir = softmax(fusion_w)
    float fw[5];
    #pragma unroll
    for (int v = 0; v < 5; ++v) fw[v] = fusw[v];
    float fmx = fw[0];
    #pragma unroll
    for (int v = 1; v < 5; ++v) fmx = fmaxf(fmx, fw[v]);
    float fsum = 0.f;
    #pragma unroll
    for (int v = 0; v < 5; ++v) { fw[v] = __expf(fw[v] - fmx); fsum += fw[v]; }
    int ii = rh * 128 + t;
    #pragma unroll
    for (int v = 0; v < 5; ++v) {
      float l = s_lp[0][t][v] + s_lp[1][t][v] + s_lp[2][t][v] + s_lp[3][t][v];
      CL[((e * 5 + v) * B + b) * C + ii] = (fw[v] / fsum) / l;
    }
  }
}

// ---------------- K3b: w-tile + GEMM vs V tiles ----------------
__global__ __launch_bounds__(256) void k_p2v(
    const float* __restrict__ Qa, const float* __restrict__ Ka,
    const float* __restrict__ Vv, const float* __restrict__ CL,
    const float* __restrict__ kmx, const float* __restrict__ kmn,
    const int* __restrict__ idx, const int* __restrict__ counts,
    float* __restrict__ out, RoutesArg R) {
  int e = blockIdx.x, b = blockIdx.y, rq = blockIdx.z;
  int t = threadIdx.x;
  int Me = counts[e];
  int r0 = rq * 64;
  if (r0 >= Me) return;

  __shared__ float s_V[64 * 128];   // V tile (64 j-rows x 128 d)
  __shared__ float s_w[64 * 65];    // combined weights, stride 65
  __shared__ float s_ka[5 * 64];

  int nbs[3] = {R.nb[e][0], R.nb[e][1], R.nb[e][2]};
  int row = t & 63;
  int i = r0 + row;
  int jq = t >> 6;
  int dg = t & 31, rg = t >> 5;

  float q[5], m[5], cl[5];
  #pragma unroll
  for (int v = 0; v < 5; ++v) {
    q[v] = Qa[((e * 5 + v) * B + b) * C + i];
    cl[v] = CL[((e * 5 + v) * B + b) * C + i];
  }
  calc_m(kmx, kmn, nbs, b, q, m);

  float acc[8][4];
  #pragma unroll
  for (int rr = 0; rr < 8; ++rr)
    #pragma unroll
    for (int k = 0; k < 4; ++k) acc[rr][k] = 0.f;

  for (int n = 0; n < 3; ++n) {
    int ne = nbs[n];
    int Mn = counts[ne];
    const float* kab = Ka + ((size_t)(ne * 5) * B + b) * C;
    const float* vvb = Vv + ((size_t)(ne * B + b)) * C * DM;
    int ntiles = (Mn + 63) >> 6;
    for (int jt = 0; jt < ntiles; ++jt) {
      int jbase = jt * 64;
      __syncthreads();  // previous tile's s_V/s_w no longer in use
      // stage Ka tile (320 floats) and V tile (8192 floats)
      if (t < 256) {
        for (int u = t; u < 5 * 64; u += 256) {
          int v = u >> 6, jj = u & 63;
          s_ka[u] = kab[v * (B * C) + jbase + jj];
        }
      }
      const float4* src = (const float4*)(vvb + (size_t)jbase * DM);
      #pragma unroll
      for (int k = 0; k < 8; ++k) ((float4*)s_V)[t + 256 * k] = src[t + 256 * k];
      __syncthreads();
      // phase A: combined weights w[row][j], each (row,j) exp'd once
      for (int jj = jq * 16; jj < jq * 16 + 16; ++jj) {
        float ww = 0.f;
        #pragma unroll
        for (int v = 0; v < 5; ++v)
          ww += cl[v] * __expf(q[v] * s_ka[v * 64 + jj] - m[v]);
        s_w[row * 65 + jj] = (jbase + jj < Mn) ? ww : 0.f;
      }
      __syncthreads();
      // phase B: acc += w-tile @ V-tile (thread: 8 rows x 4 d)
      for (int jj = 0; jj < 64; ++jj) {
        float w8[8];
        #pragma unroll
        for (int rr = 0; rr < 8; ++rr) w8[rr] = s_w[(rg * 8 + rr) * 65 + jj];
        float4 v4 = ((const float4*)(s_V + jj * DM))[dg];
        #pragma unroll
        for (int rr = 0; rr < 8; ++rr) {
          acc[rr][0] += w8[rr] * v4.x;
          acc[rr][1] += w8[rr] * v4.y;
          acc[rr][2] += w8[rr] * v4.z;
          acc[rr][3] += w8[rr] * v4.w;
        }
      }
    }
  }

  // store: rows valid-guarded, scatter by idx
  #pragma unroll
  for (int rr = 0; rr < 8; ++rr) {
    int ii = r0 + rg * 8 + rr;
    if (ii < Me) {
      int pos = idx[e * C + ii];
      float* orow = out + ((size_t)b * P + pos) * DM + dg * 4;
      float4 o4 = {acc[rr][0], acc[rr][1], acc[rr][2], acc[rr][3]};
      *(float4*)orow = o4;
    }
  }
}

// ---------------- launch ----------------
extern "C" void kernel_launch(void* const* d_in, const int* in_sizes, int n_in,
                              void* d_out, int out_size, void* d_ws, size_t ws_size,
                              hipStream_t stream) {
  const float* tokens = (const float*)d_in[0];
  const float* fingerprints = (const float*)d_in[1];
  const float* alpha = (const float*)d_in[2];
  const float* gw1 = (const float*)d_in[3];
  const float* gb1 = (const float*)d_in[4];
  const float* gw2 = (const float*)d_in[5];
  const float* gb2 = (const float*)d_in[6];
  const float* qw = (const float*)d_in[7];
  const float* kw = (const float*)d_in[8];
  const float* vw = (const float*)d_in[9];
  const float* penta = (const float*)d_in[10];
  const float* fusw = (const float*)d_in[11];
  const float* temp = (const float*)d_in[12];
  float* out = (float*)d_out;

  float* ws = (float*)d_ws;
  float* Vv = ws;                                   // [E][B][C][DM]
  float* Qa = Vv + (size_t)E * B * C * DM;          // [E][5][B][C]
  float* Ka = Qa + (size_t)E * 5 * B * C;           // [E][5][B][C]
  float* CL = Ka + (size_t)E * 5 * B * C;           // [E][5][B][C]
  float* qkd = CL + (size_t)E * 5 * B * C;          // [E][10][S]
  float* kmx = qkd + (size_t)E * NQK * S;           // [E][5][B][4]
  float* kmn = kmx + (size_t)E * 5 * B * 4;         // [E][5][B][4]
  int* idx = (int*)(kmn + (size_t)E * 5 * B * 4);   // [E][C]
  int* counts = idx + (size_t)E * C;                // [E]

  RoutesArg R;
  compute_routes(R.nb);

  hipMemsetAsync(d_out, 0, (size_t)out_size * sizeof(float), stream);
  k_prep<<<dim3(E), dim3(256), 0, stream>>>(qw, kw, penta, temp, qkd);
  k_dispatch<<<dim3(E), dim3(256), 0, stream>>>(fingerprints, idx, counts);
  k_p1<<<dim3(E, B, 4), dim3(256), 0, stream>>>(tokens, alpha, gw1, gb1, gw2, gb2,
                                                vw, qkd, idx, counts,
                                                Vv, Qa, Ka, kmx, kmn);
  k_p2l<<<dim3(E, B, 2), dim3(512), 0, stream>>>(Qa, Ka, kmx, kmn, counts, fusw, CL, R);
  k_p2v<<<dim3(E, B, 4), dim3(256), 0, stream>>>(Qa, Ka, Vv, CL, kmx, kmn, idx, counts,
                                                 out, R);
}

// Round 3
// 224.077 us; speedup vs baseline: 3.6257x; 1.1780x over previous
//
#include <hip/hip_runtime.h>
#include <cfloat>
#include <math.h>

#define E 16
#define DFULL 1024
#define DM 128
#define S 64
#define P 2048
#define B 8
#define C 256
#define W 3
#define H 16
#define NQK 10  /* 5 q-dirs then 5 k-dirs */
#define RQ 32   /* rows per block chunk */
#define NCH 8   /* row chunks per (e,b) */

struct RoutesArg { int nb[E][W]; };

// ---------------- host: replicate _expert_routes() exactly ----------------
static void compute_routes(int r[E][W]) {
  float coords[E];
  for (int i = 0; i < E; ++i) {
    double x = (double)i / (double)(E - 1);
    if (x < 1e-06) x = 1e-06;
    if (x > 1.0 - 1e-06) x = 1.0 - 1e-06;
    double val = 0.0, factor = 0.5;
    for (int k = 0; k < 8; ++k) {
      x *= 3.0;
      int d = (int)x;
      x -= (double)d;
      if (d == 2) val += factor;
      factor *= 0.5;
    }
    coords[i] = (float)val;
  }
  for (int e = 0; e < E; ++e) {
    float de[E];
    for (int i = 0; i < E; ++i) de[i] = fabsf(coords[i] - coords[e]);
    bool used[E] = {false};
    for (int w = 0; w < W; ++w) {
      int best = -1; float bd = FLT_MAX;
      for (int i = 0; i < E; ++i)
        if (!used[i] && de[i] < bd) { bd = de[i]; best = i; }  // strict < = stable
      used[best] = true;
      r[e][w] = best;
    }
  }
}

__device__ __forceinline__ float gelu_tanh(float x) {
  float x3 = x * x * x;
  return 0.5f * x * (1.0f + tanhf(0.7978845608028654f * (x + 0.044715f * x3)));
}
__device__ __forceinline__ float sigmoidf_(float x) {
  return 1.0f / (1.0f + __expf(-x));
}

// row max of valid scores: m_v = q_v * (q_v>0 ? max_k : min_k)
__device__ __forceinline__ void calc_m8(const float* __restrict__ kmx,
                                        const float* __restrict__ kmn,
                                        const int nbs[3], int b,
                                        const float q[5], float m[5]) {
  #pragma unroll
  for (int v = 0; v < 5; ++v) {
    float KX = -FLT_MAX, KN = FLT_MAX;
    #pragma unroll
    for (int n = 0; n < 3; ++n) {
      int base = ((nbs[n] * 5 + v) * B + b) * NCH;
      #pragma unroll
      for (int k = 0; k < NCH; ++k) {
        KX = fmaxf(KX, kmx[base + k]);
        KN = fminf(KN, kmn[base + k]);
      }
    }
    m[v] = (q[v] > 0.f) ? q[v] * KX : q[v] * KN;
  }
}

// ---------------- K0: dispatch + folded qd/kd (merged) ----------------
__global__ __launch_bounds__(256) void k_setup(const float* __restrict__ fp,
                                               const float* __restrict__ qw,
                                               const float* __restrict__ kw,
                                               const float* __restrict__ penta,
                                               const float* __restrict__ temp,
                                               int* __restrict__ idx,
                                               int* __restrict__ counts,
                                               float* __restrict__ qkd) {
  int e = blockIdx.x, t = threadIdx.x;
  // ---- dispatch part ----
  {
    float lo = (float)e * 0.0625f, hi = (float)(e + 1) * 0.0625f;
    bool last = (e == E - 1);
    int p0 = t * 8;
    int m[8]; int ls = 0;
    #pragma unroll
    for (int k = 0; k < 8; ++k) {
      float f = fp[p0 + k];
      bool mm = (f >= lo) && (last ? (f <= hi) : (f < hi));
      m[k] = mm ? 1 : 0;
      ls += m[k];
    }
    __shared__ int sc[256];
    sc[t] = ls;
    __syncthreads();
    for (int o = 1; o < 256; o <<= 1) {
      int v = (t >= o) ? sc[t - o] : 0;
      __syncthreads();
      sc[t] += v;
      __syncthreads();
    }
    int incl = sc[t];
    int M = sc[255];
    int r = incl - ls;
    #pragma unroll
    for (int k = 0; k < 8; ++k) {
      if (m[k]) {
        if (r < C) idx[e * C + r] = p0 + k;
        r++;
      }
    }
    if (t == 0) counts[e] = (M < C) ? M : C;
  }
  __syncthreads();
  // ---- qkd part ----
  __shared__ float s_rn[5];
  if (t < 5) {
    const float* pv = penta + (e * 5 + t) * DM;
    float ss = 0.f;
    for (int d = 0; d < DM; ++d) ss += pv[d] * pv[d];
    s_rn[t] = 1.0f / sqrtf(ss);
  }
  __syncthreads();
  float invT = 1.0f / temp[0];
  int s = t & 63, cg = t >> 6;
  for (int c = cg; c < NQK; c += 4) {
    int v = c % 5;
    bool isq = (c < 5);
    const float* wrow = (isq ? qw : kw) + ((size_t)e * S + s) * DM;
    const float* pv = penta + (e * 5 + v) * DM;
    float acc = 0.f;
    #pragma unroll
    for (int d4 = 0; d4 < DM / 4; ++d4) {
      float4 a = ((const float4*)wrow)[d4];
      float4 p = ((const float4*)pv)[d4];
      acc += a.x * p.x + a.y * p.y + a.z * p.z + a.w * p.w;
    }
    qkd[(e * NQK + c) * S + s] = acc * s_rn[v] * (isq ? invT : 1.0f);
  }
}

// ---------------- K1: gate + Qa/Ka + V, 32-row chunks ----------------
__global__ __launch_bounds__(256) void k_p1(
    const float* __restrict__ tokens, const float* __restrict__ alpha,
    const float* __restrict__ gw1, const float* __restrict__ gb1,
    const float* __restrict__ gw2, const float* __restrict__ gb2,
    const float* __restrict__ vw, const float* __restrict__ qkd,
    const int* __restrict__ idx, const int* __restrict__ counts,
    float* __restrict__ Vv, float* __restrict__ Qa, float* __restrict__ Ka,
    float* __restrict__ kmx, float* __restrict__ kmn) {
  int e = blockIdx.x, b = blockIdx.y, rq = blockIdx.z;
  int t = threadIdx.x;
  int Me = counts[e];
  int r0 = rq * RQ;

  if (r0 >= Me) {  // empty chunk: sentinels only
    if (t < 5) {
      kmx[((e * 5 + t) * B + b) * NCH + rq] = -FLT_MAX;
      kmn[((e * 5 + t) * B + b) * NCH + rq] = FLT_MAX;
    }
    return;
  }

  __shared__ float s_f[RQ * 65];      // gated feats, stride 65
  __shared__ float s_scl[RQ];
  __shared__ float s_kx[5 * RQ];
  __shared__ float s_kn[5 * RQ];
  __shared__ __align__(16) float s_U[S * DM];  // 32KB overlay region
  float* s_gw1 = s_U;                 // [S*H]   = 1024 floats (gate phase)
  float* s_gh  = s_U + 1024;          // [RQ*64] = 2048 floats (gate phase)
  float* s_qkd = s_U + 1024 + 2048;   // [640]              (until Qa/Ka done)
  float* s_vw  = s_U;                 // [S*DM] = 8192 floats (V phase)

  // stage tokens -> s_f (32 rows x 16 float4)
  #pragma unroll
  for (int k2 = 0; k2 < 2; ++k2) {
    int u = t + 256 * k2;
    int row = u >> 4, q4 = u & 15;
    int ii = r0 + row;
    int pos = (ii < Me) ? idx[e * C + ii] : idx[e * C];
    const float* trow = tokens + ((size_t)b * P + pos) * DFULL + e * S;
    float4 v4 = ((const float4*)trow)[q4];
    s_f[row * 65 + q4 * 4 + 0] = v4.x;
    s_f[row * 65 + q4 * 4 + 1] = v4.y;
    s_f[row * 65 + q4 * 4 + 2] = v4.z;
    s_f[row * 65 + q4 * 4 + 3] = v4.w;
  }
  // stage gw1 (1024 floats) and qkd (640 floats)
  ((float4*)s_gw1)[t] = ((const float4*)(gw1 + (size_t)e * S * H))[t];
  if (t < 160) ((float4*)s_qkd)[t] = ((const float4*)(qkd + e * NQK * S))[t];
  __syncthreads();

  // gate partials: 4 threads per row, 16 s each
  if (t < 128) {
    int row = t >> 2, sq = t & 3;
    float hh[H];
    #pragma unroll
    for (int j = 0; j < H; ++j) hh[j] = 0.f;
    #pragma unroll
    for (int k = 0; k < 16; ++k) {
      int s = sq * 16 + k;
      float fs = s_f[row * 65 + s];
      const float* gr = s_gw1 + s * H;
      #pragma unroll
      for (int j = 0; j < H; ++j) hh[j] += fs * gr[j];
    }
    #pragma unroll
    for (int j = 0; j < H; ++j) s_gh[(row * 4 + sq) * H + j] = hh[j];
  }
  __syncthreads();
  if (t < RQ) {
    float z = gb2[e];
    #pragma unroll
    for (int j = 0; j < H; ++j) {
      float hj = gb1[e * H + j] + s_gh[(t * 4 + 0) * H + j] + s_gh[(t * 4 + 1) * H + j] +
                 s_gh[(t * 4 + 2) * H + j] + s_gh[(t * 4 + 3) * H + j];
      z += gelu_tanh(hj) * gw2[e * H + j];
    }
    float aw = sigmoidf_(alpha[e]);
    s_scl[t] = sigmoidf_(z) * aw + (1.0f - aw);
  }
  __syncthreads();
  // scale feats in place
  {
    int row = t >> 3, s0 = (t & 7) * 8;
    float sc = s_scl[row];
    #pragma unroll
    for (int k = 0; k < 8; ++k) s_f[row * 65 + s0 + k] *= sc;
  }
  __syncthreads();

  // Qa/Ka: thread (row=t&31, c = t>>5 and t>>5+8)
  {
    int row = t & 31, c0 = t >> 5;
    int ii = r0 + row;
    bool val = (ii < Me);
    for (int c = c0; c < NQK; c += 8) {
      float a = 0.f;
      #pragma unroll
      for (int s = 0; s < S; ++s) a += s_f[row * 65 + s] * s_qkd[c * S + s];
      int v = c % 5;
      if (c < 5) {
        if (val) Qa[((e * 5 + v) * B + b) * C + ii] = a;
      } else {
        if (val) Ka[((e * 5 + v) * B + b) * C + ii] = a;
        s_kx[v * RQ + row] = val ? a : -FLT_MAX;
        s_kn[v * RQ + row] = val ? a : FLT_MAX;
      }
    }
  }
  __syncthreads();
  if (t < 5) {
    float mx = -FLT_MAX, mn = FLT_MAX;
    for (int r = 0; r < RQ; ++r) {
      mx = fmaxf(mx, s_kx[t * RQ + r]);
      mn = fminf(mn, s_kn[t * RQ + r]);
    }
    kmx[((e * 5 + t) * B + b) * NCH + rq] = mx;
    kmn[((e * 5 + t) * B + b) * NCH + rq] = mn;
  }
  __syncthreads();  // s_qkd dead; overlay with vw

  // stage vw (8192 floats = 2048 float4)
  #pragma unroll
  for (int k = 0; k < 8; ++k)
    ((float4*)s_vw)[t + 256 * k] = ((const float4*)(vw + (size_t)e * S * DM))[t + 256 * k];
  __syncthreads();

  // V = feats @ v_w : thread (row=t&31, 16-d chunk)
  {
    int row = t & 31, dch = (t >> 5) * 16;
    float acc[16];
    #pragma unroll
    for (int k = 0; k < 16; ++k) acc[k] = 0.f;
    for (int s = 0; s < S; ++s) {
      float fs = s_f[row * 65 + s];
      const float* vr = s_vw + s * DM + dch;
      #pragma unroll
      for (int k = 0; k < 16; ++k) acc[k] += fs * vr[k];
    }
    int ii = r0 + row;
    if (ii < Me) {
      float* vo = Vv + (((size_t)(e * B + b)) * C + ii) * DM + dch;
      #pragma unroll
      for (int k = 0; k < 16; k += 4) {
        float4 o4 = {acc[k], acc[k + 1], acc[k + 2], acc[k + 3]};
        *(float4*)(vo + k) = o4;
      }
    }
  }
}

// ---------------- K2: fused l-pass + w-tile + GEMM ----------------
__global__ __launch_bounds__(256) void k_p2v(
    const float* __restrict__ Qa, const float* __restrict__ Ka,
    const float* __restrict__ Vv, const float* __restrict__ kmx,
    const float* __restrict__ kmn, const int* __restrict__ idx,
    const int* __restrict__ counts, const float* __restrict__ fusw,
    float* __restrict__ out, RoutesArg R) {
  int e = blockIdx.x, b = blockIdx.y, rq = blockIdx.z;
  int t = threadIdx.x;
  int Me = counts[e];
  int r0 = rq * RQ;
  if (r0 >= Me) return;

  __shared__ float s_V[64 * DM];     // 32KB V tile
  __shared__ float s_wT[64 * 36];    // w transposed [jj][row], stride 36
  __shared__ float s_ka[5 * 64];
  __shared__ float s_lp[8 * 5 * RQ];

  int nbs[3] = {R.nb[e][0], R.nb[e][1], R.nb[e][2]};
  int row = t & 31, jq = t >> 5;
  int ii = r0 + row;

  float q[5], m[5];
  #pragma unroll
  for (int v = 0; v < 5; ++v) q[v] = Qa[((e * 5 + v) * B + b) * C + ii];
  calc_m8(kmx, kmn, nbs, b, q, m);

  // l-pass: 8-way j-split per row
  float lp[5] = {0.f, 0.f, 0.f, 0.f, 0.f};
  for (int n = 0; n < 3; ++n) {
    int ne = nbs[n];
    int Mn = counts[ne];
    const float* kb = Ka + ((size_t)(ne * 5) * B + b) * C;
    for (int j = jq; j < Mn; j += 8) {
      #pragma unroll
      for (int v = 0; v < 5; ++v)
        lp[v] += __expf(q[v] * kb[v * (B * C) + j] - m[v]);
    }
  }
  #pragma unroll
  for (int v = 0; v < 5; ++v) s_lp[(jq * 5 + v) * RQ + row] = lp[v];
  __syncthreads();

  // wdir = softmax(fusion_w); cl = wdir/l
  float fw[5];
  #pragma unroll
  for (int v = 0; v < 5; ++v) fw[v] = fusw[v];
  float fmx = fw[0];
  #pragma unroll
  for (int v = 1; v < 5; ++v) fmx = fmaxf(fmx, fw[v]);
  float fsum = 0.f;
  #pragma unroll
  for (int v = 0; v < 5; ++v) { fw[v] = __expf(fw[v] - fmx); fsum += fw[v]; }
  float cl[5];
  #pragma unroll
  for (int v = 0; v < 5; ++v) {
    float l = 0.f;
    #pragma unroll
    for (int g = 0; g < 8; ++g) l += s_lp[(g * 5 + v) * RQ + row];
    cl[v] = (fw[v] / fsum) / l;
  }

  int dg = t & 31, rg = t >> 5;
  float acc[4][4];
  #pragma unroll
  for (int rr = 0; rr < 4; ++rr)
    #pragma unroll
    for (int k = 0; k < 4; ++k) acc[rr][k] = 0.f;

  for (int n = 0; n < 3; ++n) {
    int ne = nbs[n];
    int Mn = counts[ne];
    const float* kab = Ka + ((size_t)(ne * 5) * B + b) * C;
    const float* vvb = Vv + ((size_t)(ne * B + b)) * C * DM;
    int ntiles = (Mn + 63) >> 6;
    for (int jt = 0; jt < ntiles; ++jt) {
      int jbase = jt * 64;
      __syncthreads();  // protect previous tile
      for (int u = t; u < 5 * 64; u += 256) {
        int v = u >> 6, jj = u & 63;
        s_ka[u] = kab[v * (B * C) + jbase + jj];
      }
      const float4* src = (const float4*)(vvb + (size_t)jbase * DM);
      #pragma unroll
      for (int k = 0; k < 8; ++k) ((float4*)s_V)[t + 256 * k] = src[t + 256 * k];
      __syncthreads();
      // phase A: w[jj][row], each (row,jj) exp'd once; thread: (row, 8 jj)
      #pragma unroll
      for (int j8 = 0; j8 < 8; ++j8) {
        int jj = jq * 8 + j8;
        float ww = 0.f;
        #pragma unroll
        for (int v = 0; v < 5; ++v)
          ww += cl[v] * __expf(q[v] * s_ka[v * 64 + jj] - m[v]);
        s_wT[jj * 36 + row] = (jbase + jj < Mn) ? ww : 0.f;
      }
      __syncthreads();
      // phase B: acc += wT @ V (thread: 4 rows x 4 d)
      for (int jj = 0; jj < 64; ++jj) {
        float4 w4 = *(const float4*)&s_wT[jj * 36 + rg * 4];
        float4 v4 = *(const float4*)&s_V[jj * DM + dg * 4];
        acc[0][0] += w4.x * v4.x; acc[0][1] += w4.x * v4.y;
        acc[0][2] += w4.x * v4.z; acc[0][3] += w4.x * v4.w;
        acc[1][0] += w4.y * v4.x; acc[1][1] += w4.y * v4.y;
        acc[1][2] += w4.y * v4.z; acc[1][3] += w4.y * v4.w;
        acc[2][0] += w4.z * v4.x; acc[2][1] += w4.z * v4.y;
        acc[2][2] += w4.z * v4.z; acc[2][3] += w4.z * v4.w;
        acc[3][0] += w4.w * v4.x; acc[3][1] += w4.w * v4.y;
        acc[3][2] += w4.w * v4.z; acc[3][3] += w4.w * v4.w;
      }
    }
  }

  // store (disjoint per block: row-chunk partition)
  #pragma unroll
  for (int rr = 0; rr < 4; ++rr) {
    int ir = r0 + rg * 4 + rr;
    if (ir < Me) {
      int pos = idx[e * C + ir];
      float* orow = out + ((size_t)b * P + pos) * DM + dg * 4;
      float4 o4 = {acc[rr][0], acc[rr][1], acc[rr][2], acc[rr][3]};
      *(float4*)orow = o4;
    }
  }
}

// ---------------- launch ----------------
extern "C" void kernel_launch(void* const* d_in, const int* in_sizes, int n_in,
                              void* d_out, int out_size, void* d_ws, size_t ws_size,
                              hipStream_t stream) {
  const float* tokens = (const float*)d_in[0];
  const float* fingerprints = (const float*)d_in[1];
  const float* alpha = (const float*)d_in[2];
  const float* gw1 = (const float*)d_in[3];
  const float* gb1 = (const float*)d_in[4];
  const float* gw2 = (const float*)d_in[5];
  const float* gb2 = (const float*)d_in[6];
  const float* qw = (const float*)d_in[7];
  const float* kw = (const float*)d_in[8];
  const float* vw = (const float*)d_in[9];
  const float* penta = (const float*)d_in[10];
  const float* fusw = (const float*)d_in[11];
  const float* temp = (const float*)d_in[12];
  float* out = (float*)d_out;

  float* ws = (float*)d_ws;
  float* Vv = ws;                                    // [E][B][C][DM]
  float* Qa = Vv + (size_t)E * B * C * DM;           // [E][5][B][C]
  float* Ka = Qa + (size_t)E * 5 * B * C;            // [E][5][B][C]
  float* qkd = Ka + (size_t)E * 5 * B * C;           // [E][10][S]
  float* kmx = qkd + (size_t)E * NQK * S;            // [E][5][B][NCH]
  float* kmn = kmx + (size_t)E * 5 * B * NCH;        // [E][5][B][NCH]
  int* idx = (int*)(kmn + (size_t)E * 5 * B * NCH);  // [E][C]
  int* counts = idx + (size_t)E * C;                 // [E]

  RoutesArg R;
  compute_routes(R.nb);

  hipMemsetAsync(d_out, 0, (size_t)out_size * sizeof(float), stream);
  k_setup<<<dim3(E), dim3(256), 0, stream>>>(fingerprints, qw, kw, penta, temp,
                                             idx, counts, qkd);
  k_p1<<<dim3(E, B, NCH), dim3(256), 0, stream>>>(tokens, alpha, gw1, gb1, gw2, gb2,
                                                  vw, qkd, idx, counts,
                                                  Vv, Qa, Ka, kmx, kmn);
  k_p2v<<<dim3(E, B, NCH), dim3(256), 0, stream>>>(Qa, Ka, Vv, kmx, kmn, idx, counts,
                                                   fusw, out, R);
}